// Round 1
// baseline (117.586 us; speedup 1.0000x reference)
//
#include <hip/hip_runtime.h>

// TrigoLinear: out[b,o] = sum_i sin(x[b,i]*w_sin[o,i] + b_sin[o,i]) * w_out[o,i] + b_out[o]
// B=1024, IN=512, OUT=512, fp32.
// Compute-bound on VALU (268M sin+2fma). Layout: lanes->b (x float4 loads,
// line-reuse), o from blockIdx.y only (uniform -> weight/bias via s_load/K$).

#define B_DIM   1024
#define IN_DIM  512
#define OUT_DIM 512
#define OT      2      // output channels per thread
#define BLK     256    // threads per block

__global__ __launch_bounds__(BLK, 4) void trigo_kernel(
    const float* __restrict__ x,       // (B, IN)
    const float* __restrict__ weight,  // (OUT, IN, 2): [...,0]=w_out, [...,1]=w_sin
    const float* __restrict__ bias,    // (OUT, IN+1): [:, :IN]=b_sin, [:, IN]=b_out
    float* __restrict__ out)           // (B, OUT)
{
    constexpr float INV2PI = 0.15915494309189535f;

    const int b  = blockIdx.x * BLK + threadIdx.x;   // lane-varying
    const int o0 = blockIdx.y * OT;                  // block-uniform -> s_load path

    const float4* x4 = reinterpret_cast<const float4*>(x + (size_t)b * IN_DIM);

    float acc[OT];
#pragma unroll
    for (int j = 0; j < OT; ++j) acc[j] = 0.0f;

    for (int ii = 0; ii < IN_DIM; ii += 4) {
        float4 xv = x4[ii >> 2];
        float xs[4] = {xv.x, xv.y, xv.z, xv.w};

#pragma unroll
        for (int j = 0; j < OT; ++j) {
            const int o = o0 + j;
            // float2 view of weight row o: element i = (w_out[o][i], w_sin[o][i])
            const float2* wp = reinterpret_cast<const float2*>(
                                   weight + (size_t)o * IN_DIM * 2) + ii;
            const float* bp = bias + (size_t)o * (IN_DIM + 1) + ii;
#pragma unroll
            for (int k = 0; k < 4; ++k) {
                float2 w  = wp[k];          // uniform -> scalar load
                float  bs = bp[k];          // uniform -> scalar load
                float  a  = fmaf(xs[k], w.y, bs);
                float  s  = __builtin_amdgcn_sinf(a * INV2PI);  // v_sin_f32, rev input
                acc[j] = fmaf(s, w.x, acc[j]);
            }
        }
    }

#pragma unroll
    for (int j = 0; j < OT; ++j) {
        const int o = o0 + j;
        acc[j] += bias[(size_t)o * (IN_DIM + 1) + IN_DIM];   // b_out[o]
    }

    // OT=2 adjacent o's -> single 8B store per thread
    float2 r = make_float2(acc[0], acc[1]);
    *reinterpret_cast<float2*>(out + (size_t)b * OUT_DIM + o0) = r;
}

extern "C" void kernel_launch(void* const* d_in, const int* in_sizes, int n_in,
                              void* d_out, int out_size, void* d_ws, size_t ws_size,
                              hipStream_t stream) {
    const float* x      = (const float*)d_in[0];
    const float* weight = (const float*)d_in[1];
    const float* bias   = (const float*)d_in[2];
    float* out          = (float*)d_out;

    dim3 grid(B_DIM / BLK, OUT_DIM / OT);
    dim3 block(BLK);
    trigo_kernel<<<grid, block, 0, stream>>>(x, weight, bias, out);
}

// Round 2
// 107.855 us; speedup vs baseline: 1.0902x; 1.0902x over previous
//
#include <hip/hip_runtime.h>

// TrigoLinear: out[b,o] = sum_i sin(x[b,i]*w_sin[o,i] + b_sin[o,i]) * w_out[o,i] + b_out[o]
// B=1024, IN=512, OUT=512, fp32. VALU-bound (v_sin + 2 fma per element).
//
// R2 design:
//  - prep kernels build in d_ws: xt (x transposed to (IN/4, B) float4 -> coalesced
//    main-kernel loads), wf[o][i] = (w_sin/2pi, w_out) float2, bf[o][i] = b_sin/2pi,
//    bout[o]. Pre-scaling kills the per-element v_mul (v_sin_f32 takes revolutions).
//  - main: OT=1, o = blockIdx.x (uniform -> s_load weights via K$), lane->b.
//    grid (512 o, 4 b-chunks), o-fastest => consecutive blocks share x slice in L2.
//    8192 waves = 100% occupancy cap; 4 accumulators break the acc chain.

#define B_DIM   1024
#define IN_DIM  512
#define OUT_DIM 512
#define BLK     256

// ws layout in floats
#define XT_OFF   0            // float4[IN/4][B]   : 524288 floats (2 MB)
#define WF_OFF   524288       // float2[OUT][IN]   : 524288 floats (2 MB)
#define BF_OFF   1048576      // float [OUT][IN]   : 262144 floats (1 MB)
#define BOUT_OFF 1310720      // float [OUT]       : 512 floats

__global__ __launch_bounds__(BLK) void prep_x_kernel(
    const float* __restrict__ x, float* __restrict__ ws)
{
    // tid = b*128 + q  (q = i-quad). Coalesced float4 read, scattered write (2 MB, cheap).
    int tid = blockIdx.x * BLK + threadIdx.x;        // [0, 131072)
    int b = tid >> 7;
    int q = tid & 127;
    float4 v = reinterpret_cast<const float4*>(x)[tid];
    reinterpret_cast<float4*>(ws + XT_OFF)[q * B_DIM + b] = v;
}

__global__ __launch_bounds__(BLK) void prep_w_kernel(
    const float* __restrict__ weight, const float* __restrict__ bias,
    float* __restrict__ ws)
{
    constexpr float INV2PI = 0.15915494309189535f;
    int tid = blockIdx.x * BLK + threadIdx.x;        // [0, 262144)
    int o = tid >> 9;
    int i = tid & 511;
    // weight[o][i][0..1] = (w_out, w_sin) -> contiguous float2
    float2 w = reinterpret_cast<const float2*>(weight)[tid];
    float bs = bias[o * (IN_DIM + 1) + i];
    reinterpret_cast<float2*>(ws + WF_OFF)[tid] = make_float2(w.y * INV2PI, w.x);
    (ws + BF_OFF)[tid] = bs * INV2PI;
    if (i == 0)
        (ws + BOUT_OFF)[o] = bias[o * (IN_DIM + 1) + IN_DIM];
}

__global__ __launch_bounds__(BLK, 8) void trigo_kernel(
    const float* __restrict__ ws, float* __restrict__ out)
{
    const int o = blockIdx.x;                        // block-uniform -> s_load path
    const int b = blockIdx.y * BLK + threadIdx.x;    // lane-varying, coalesced

    const float4* xt4  = reinterpret_cast<const float4*>(ws + XT_OFF);
    const float2* wrow = reinterpret_cast<const float2*>(ws + WF_OFF) + o * IN_DIM;
    const float*  brow = ws + BF_OFF + o * IN_DIM;

    float acc0 = 0.f, acc1 = 0.f, acc2 = 0.f, acc3 = 0.f;

#pragma unroll 4
    for (int q = 0; q < IN_DIM / 4; ++q) {
        float4 xv = xt4[q * B_DIM + b];              // 1 KB contiguous per wave
        float2 w0 = wrow[q * 4 + 0];                 // uniform -> scalar loads
        float2 w1 = wrow[q * 4 + 1];
        float2 w2 = wrow[q * 4 + 2];
        float2 w3 = wrow[q * 4 + 3];
        float  a0 = fmaf(xv.x, w0.x, brow[q * 4 + 0]);
        float  a1 = fmaf(xv.y, w1.x, brow[q * 4 + 1]);
        float  a2 = fmaf(xv.z, w2.x, brow[q * 4 + 2]);
        float  a3 = fmaf(xv.w, w3.x, brow[q * 4 + 3]);
        acc0 = fmaf(__builtin_amdgcn_sinf(a0), w0.y, acc0);
        acc1 = fmaf(__builtin_amdgcn_sinf(a1), w1.y, acc1);
        acc2 = fmaf(__builtin_amdgcn_sinf(a2), w2.y, acc2);
        acc3 = fmaf(__builtin_amdgcn_sinf(a3), w3.y, acc3);
    }

    float res = ((acc0 + acc1) + (acc2 + acc3)) + (ws + BOUT_OFF)[o];
    out[(size_t)b * OUT_DIM + o] = res;              // scattered 4B store, 2 MB total
}

extern "C" void kernel_launch(void* const* d_in, const int* in_sizes, int n_in,
                              void* d_out, int out_size, void* d_ws, size_t ws_size,
                              hipStream_t stream) {
    const float* x      = (const float*)d_in[0];
    const float* weight = (const float*)d_in[1];
    const float* bias   = (const float*)d_in[2];
    float* out          = (float*)d_out;
    float* ws           = (float*)d_ws;

    prep_x_kernel<<<dim3((B_DIM * IN_DIM / 4) / BLK), dim3(BLK), 0, stream>>>(x, ws);
    prep_w_kernel<<<dim3((OUT_DIM * IN_DIM) / BLK), dim3(BLK), 0, stream>>>(weight, bias, ws);

    dim3 grid(OUT_DIM, B_DIM / BLK);                 // o fastest -> L2 x-slice sharing
    trigo_kernel<<<grid, dim3(BLK), 0, stream>>>(ws, out);
}